// Round 5
// baseline (662.857 us; speedup 1.0000x reference)
//
#include <hip/hip_runtime.h>
#include <hip/hip_bf16.h>

// PixelContrastLossOnlyNeg on MI355X.
// feats [16,256,128,128] f32, queue [256,256] f32, labels [262144,256] i32 -> scalar f32.
// R5: decompose into pure streaming kernels (fill-kernel-shaped; harness fill
// proves 6.7 TB/s is reachable with shallow-dependence memory kernels):
//   fprep: feats -> bf16 B-fragment-ordered tiles (256MB r, 128MB w)
//   lcomp: labels -> 8MB bitmask planes        (256MB r, 8MB w)
//   pcl_main: GEMM+loss, reads 32KB contiguous bf16/tile via global_load_lds
//             (136MB r) — staging is 8 DMA instrs/wave, zero VALU.
// Total ~920MB @ streaming rates; trades 1.8x traffic for latency-insensitivity.

typedef __bf16 bf16x8 __attribute__((ext_vector_type(8)));
typedef float floatx4 __attribute__((ext_vector_type(4)));

using gl_void = const __attribute__((address_space(1))) void;
using lds_void = __attribute__((address_space(3))) void;

#define N_PIX 262144

// Pack two f32 -> two bf16 (round-half-up).
__device__ __forceinline__ unsigned int pack_bf2(float a, float b) {
  unsigned int ua = __float_as_uint(a) + 0x8000u;
  unsigned int ub = __float_as_uint(b) + 0x8000u;
  return (ua >> 16) | (ub & 0xffff0000u);
}

// ---------------------------------------------------------------------------
// k0: queue f32 -> bf16 * (1/T), pre-swizzled in A-fragment lane order.
// Also zeroes global accumulators.
// ---------------------------------------------------------------------------
__global__ void qprep(const float* __restrict__ queue,
                      unsigned short* __restrict__ qs,
                      float* __restrict__ accum) {
  const int gt = blockIdx.x * 256 + threadIdx.x;  // 0..8191
  const int t = gt >> 6;
  const int lane = gt & 63;
  const int m = ((t >> 3) << 4) | (lane & 15);
  const int k0 = ((t & 7) << 5) | ((lane >> 4) << 3);
  const float* qr = queue + m * 256 + k0;
  const float TINV = 14.2857142857142857f;
  union { unsigned int u32[4]; uint4 v; } u;
#pragma unroll
  for (int j = 0; j < 4; ++j)
    u.u32[j] = pack_bf2(qr[2 * j] * TINV, qr[2 * j + 1] * TINV);
  *(uint4*)(qs + (size_t)gt * 8) = u.v;
  if (gt == 0) { accum[0] = 0.0f; accum[1] = 0.0f; }
}

// ---------------------------------------------------------------------------
// k1: fprep. feats f32 -> bf16 tiles in MFMA B-fragment order.
// Tile T (64 pixels) occupies 32KB at ptiles + T*2048 uint4s; frag slot for
// (kg = ch>>3, n = pixel): (((kg>>2)<<2) + (n>>4))*64 + ((kg&3)<<4) + (n&15).
// Block b: tile T = b>>3, channel group cg = b&7 (32 ch); wave w handles
// channels cg*32 + w*8 .. +8, lane = pixel. 8 coalesced 256B loads -> 4 packs
// -> 1 coalesced store (4x256B segments). Pure stream, shallow dependence.
// ---------------------------------------------------------------------------
__global__ __launch_bounds__(256) void fprep(const float* __restrict__ feats,
                                             uint4* __restrict__ ptiles) {
  const int b = blockIdx.x;
  const int T = b >> 3;
  const int cg = b & 7;
  const int w = threadIdx.x >> 6;
  const int lane = threadIdx.x & 63;   // pixel n
  const int kg = (cg << 2) + w;        // k-group 0..31
  const int batch = T >> 8;
  const int pix0 = (T & 255) << 6;

  const float* gp = feats + ((size_t)batch << 22) + ((size_t)(kg << 3) << 14) +
                    pix0 + lane;
  float f[8];
#pragma unroll
  for (int j = 0; j < 8; ++j) f[j] = gp[(size_t)j << 14];

  uint4 u;
  u.x = pack_bf2(f[0], f[1]);
  u.y = pack_bf2(f[2], f[3]);
  u.z = pack_bf2(f[4], f[5]);
  u.w = pack_bf2(f[6], f[7]);
  ptiles[(size_t)T * 2048 +
         ((((kg >> 2) << 2) + (lane >> 4)) << 6) + ((kg & 3) << 4) + (lane & 15)] = u;
}

// ---------------------------------------------------------------------------
// k2: label compress. labels[N_PIX][256] i32 -> maskT[8][N_PIX] u32 planes,
// plane j bit b of maskT[j][p] = (labels[p][32j+b] != 0).
// ---------------------------------------------------------------------------
__global__ __launch_bounds__(256) void lcomp(const int* __restrict__ labels,
                                             unsigned* __restrict__ maskT) {
  const int tid = threadIdx.x;
  const int lane = tid & 63;
  const int wave = (blockIdx.x << 2) + (tid >> 6);
  const int p0 = wave << 6;  // 64 pixels per wave
  const int* lb = labels + ((size_t)p0 << 8) + (lane << 2);
  const int sh = (lane & 7) << 2;
  const bool writer = (lane & 7) == 0;
  unsigned* wp = maskT + ((size_t)(lane >> 3) * N_PIX) + p0;

#pragma unroll
  for (int c8 = 0; c8 < 8; ++c8) {
    int4 lv[8];
#pragma unroll
    for (int i = 0; i < 8; ++i)
      lv[i] = *(const int4*)(lb + (((c8 << 3) + i) << 8));
#pragma unroll
    for (int i = 0; i < 8; ++i) {
      unsigned v = ((lv[i].x != 0) ? 1u : 0u) | ((lv[i].y != 0) ? 2u : 0u) |
                   ((lv[i].z != 0) ? 4u : 0u) | ((lv[i].w != 0) ? 8u : 0u);
      v <<= sh;
      v |= __shfl_xor(v, 1);
      v |= __shfl_xor(v, 2);
      v |= __shfl_xor(v, 4);
      if (writer) wp[(c8 << 3) + i] = v;
    }
  }
}

// ---------------------------------------------------------------------------
// k3: main fused kernel. Block = 64 pixels x 256 classes, 256 threads (4
// waves), wave w owns classes [64w, 64w+64). Grid = 4096 tiles.
// Stage = 8 global_load_lds dwordx4 per wave (32KB contiguous, frag-ordered,
// zero VALU) + 8 mask dwords into VGPRs. Epilogue pure VALU.
// ---------------------------------------------------------------------------
__global__ __launch_bounds__(256, 4) void pcl_main(
    const uint4* __restrict__ ptiles,
    const unsigned* __restrict__ maskT,
    const unsigned short* __restrict__ qs,
    float* __restrict__ accum) {
  __shared__ uint4 Bs[2048];       // 32 KB bf16 B-frags (DMA'd, already packed)
  __shared__ float Red[8][64];     // 2 KB per-wave nn/pp partials

  const int T = blockIdx.x;
  const int tid = threadIdx.x;
  const int w = tid >> 6;
  const int lane = tid & 63;
  const int qd = lane >> 4;
  const int s = lane & 15;
  const int pix0 = T << 6;

  // ---- stage: 8 DMA instrs/wave, each 1KB contiguous (lane-ordered) ----
  {
    const char* gsrc = (const char*)(ptiles + (size_t)T * 2048) +
                       ((w << 3) << 10) + (lane << 4);
#pragma unroll
    for (int i = 0; i < 8; ++i) {
      uint4* lp = &Bs[((w << 3) + i) << 6];
      __builtin_amdgcn_global_load_lds((gl_void*)(gsrc + (i << 10)),
                                       (lds_void*)lp, 16, 0, 0);
    }
  }

  // ---- masks: wave w needs planes 2w, 2w+1; lane covers pixels 16nt+s ----
  unsigned mk[2][4];
#pragma unroll
  for (int j = 0; j < 2; ++j)
#pragma unroll
    for (int nt = 0; nt < 4; ++nt)
      mk[j][nt] = maskT[(size_t)((w << 1) + j) * N_PIX + pix0 + (nt << 4) + s];

  floatx4 acc[4][4];
#pragma unroll
  for (int mt = 0; mt < 4; ++mt)
#pragma unroll
    for (int nt = 0; nt < 4; ++nt)
      acc[mt][nt] = floatx4{0.0f, 0.0f, 0.0f, 0.0f};

  __syncthreads();  // drains DMA + mask loads

  // ---- K loop: 8 steps of 32; 4 A dwordx4 (L2-hot) + 4 ds_read_b128 + 16 MFMA ----
  const bf16x8* qfrag = (const bf16x8*)qs;
  const bf16x8* Bf = (const bf16x8*)Bs;
#pragma unroll
  for (int ks = 0; ks < 8; ++ks) {
    bf16x8 af[4];
#pragma unroll
    for (int mt = 0; mt < 4; ++mt)
      af[mt] = qfrag[(((((w << 2) + mt) << 3) | ks) << 6) + lane];
    bf16x8 bfv[4];
#pragma unroll
    for (int nt = 0; nt < 4; ++nt)
      bfv[nt] = Bf[(((ks << 2) + nt) << 6) + lane];
#pragma unroll
    for (int mt = 0; mt < 4; ++mt)
#pragma unroll
      for (int nt = 0; nt < 4; ++nt)
        acc[mt][nt] = __builtin_amdgcn_mfma_f32_16x16x32_bf16(af[mt], bfv[nt],
                                                              acc[mt][nt], 0, 0, 0);
  }

  // ---- epilogue: pure VALU. class m = 64w+16mt+4qd+r -> plane 2w+(mt>>1),
  //      bit ((mt&1)<<4) + (qd<<2) + r ----
  float nn[4] = {0.f, 0.f, 0.f, 0.f};
  float pp[4] = {0.f, 0.f, 0.f, 0.f};
#pragma unroll
  for (int mt = 0; mt < 4; ++mt) {
#pragma unroll
    for (int nt = 0; nt < 4; ++nt) {
      const floatx4 a = acc[mt][nt];
      const unsigned mw = mk[mt >> 1][nt];
      const unsigned base = ((mt & 1) << 4) | (qd << 2);
#pragma unroll
      for (int r = 0; r < 4; ++r) {
        const unsigned p = (mw >> (base + r)) & 1u;
        const float ls = __uint_as_float(__float_as_uint(a[r]) ^ (p << 31));
        const float e = __expf(ls);
        nn[nt] += p ? 0.0f : e;
        pp[nt] += p ? e : 0.0f;
      }
    }
  }

  // quad-reduce (lanes l, l+16, l+32, l+48 share a pixel)
#pragma unroll
  for (int nt = 0; nt < 4; ++nt) {
    nn[nt] += __shfl_xor(nn[nt], 16);
    nn[nt] += __shfl_xor(nn[nt], 32);
    pp[nt] += __shfl_xor(pp[nt], 16);
    pp[nt] += __shfl_xor(pp[nt], 32);
  }
  if (lane < 16) {
#pragma unroll
    for (int nt = 0; nt < 4; ++nt) {
      Red[(w << 1) | 0][(nt << 4) + lane] = nn[nt];
      Red[(w << 1) | 1][(nt << 4) + lane] = pp[nt];
    }
  }
  __syncthreads();

  if (tid < 64) {
    const float sn = Red[0][tid] + Red[2][tid] + Red[4][tid] + Red[6][tid];
    const float sp = Red[1][tid] + Red[3][tid] + Red[5][tid] + Red[7][tid];
    float loss = logf(sn * sp + 1.0f);
    float c = (loss != 0.0f) ? 1.0f : 0.0f;
#pragma unroll
    for (int off = 32; off > 0; off >>= 1) {
      loss += __shfl_xor(loss, off);
      c += __shfl_xor(c, off);
    }
    if (tid == 0) {
      atomicAdd(&accum[0], loss);
      atomicAdd(&accum[1], c);
    }
  }
}

// ---------------------------------------------------------------------------
// k4: scalar finalize. Mirrors where(lb_num==0, 0, sum/max(lb_num,1)).
// ---------------------------------------------------------------------------
__global__ void pcl_finalize(const float* __restrict__ accum,
                             float* __restrict__ out) {
  const float ssum = accum[0];
  const float c = accum[1];
  out[0] = (c != 0.0f) ? (ssum / c) : 0.0f;
}

extern "C" void kernel_launch(void* const* d_in, const int* in_sizes, int n_in,
                              void* d_out, int out_size, void* d_ws, size_t ws_size,
                              hipStream_t stream) {
  (void)in_sizes; (void)n_in; (void)out_size; (void)ws_size;
  const float* feats = (const float*)d_in[0];
  const float* queue = (const float*)d_in[1];
  const int* labels = (const int*)d_in[2];

  // ws layout: [0,128MB) ptiles; [128MB,+8MB) maskT; then qs 128KB; accum.
  uint4* ptiles = (uint4*)d_ws;
  unsigned* maskT = (unsigned*)((char*)d_ws + ((size_t)4096 * 32768));
  unsigned short* qs = (unsigned short*)((char*)maskT + (size_t)8 * N_PIX * 4);
  float* accum = (float*)((char*)qs + 256 * 256 * sizeof(unsigned short));

  qprep<<<32, 256, 0, stream>>>(queue, qs, accum);
  fprep<<<32768, 256, 0, stream>>>(feats, ptiles);
  lcomp<<<1024, 256, 0, stream>>>(labels, maskT);
  pcl_main<<<4096, 256, 0, stream>>>(ptiles, maskT, qs, accum);
  pcl_finalize<<<1, 1, 0, stream>>>(accum, (float*)d_out);
}